// Round 11
// baseline (116.536 us; speedup 1.0000x reference)
//
#include <hip/hip_runtime.h>
#include <math.h>

typedef __bf16 b16x8 __attribute__((ext_vector_type(8)));
typedef float  f32x4 __attribute__((ext_vector_type(4)));
typedef float  f32x2 __attribute__((ext_vector_type(2)));

#define B_    8
#define CIN_  64
#define COUT_ 64
#define Hs    96
#define Ws    96
#define PLANE (Hs*Ws)        // 9216
#define IMG   (CIN_*PLANE)   // 589824
#define NP    (B_*PLANE)     // 73728
#define NBLK  (NP/64)        // 1152 blocks, 64 px each as a 4-row x 16-col tile

// LDS window for a 4x16 tile with +/-1 offset margin:
// rows h0-2..h0+6 (9), cols c0-2..c0+18 (21). Offsets are ~N(0,0.24) so
// |d|>1 is ~3e-5; the exact global fallback handles those lanes.
#define WR 9
#define WC 21
#define WPIX (WR*WC)         // 189
#define WSTG 192             // padded to 6 full 256-thread stage rounds
#define WBYTES (WSTG*128)    // 24576 B

__device__ __forceinline__ int swz(int bid) { return (bid & 7) * (NBLK / 8) + (bid >> 3); }

// prep (R9/R10): xpose at HALF a pixel (32 channels) per thread, blocks
// [0,576) -> 2.8 blocks/CU. Reads: even/odd lanes split channel halves,
// 2x128-B segments per instr. Writes: 64 B/lane, consecutive lanes
// contiguous (4 KB per wave-instr). [576,720) = weight repack.
__global__ void prep_xpose(const float* __restrict__ x,
                           const float* __restrict__ weight, const float* __restrict__ w_off,
                           __bf16* __restrict__ xT,
                           __bf16* __restrict__ wAB, __bf16* __restrict__ wAO) {
    int bid = blockIdx.x;
    if (bid < 576) {
        int idx  = bid * 256 + threadIdx.x;   // 147456 = 2*NP half-pixel jobs
        int p    = idx >> 1;                  // pixel
        int half = idx & 1;                   // channel half: half*32..+31
        int b = p / PLANE, r = p - b * PLANE;
        const float* src = x + b * IMG + (size_t)half * 32 * PLANE + r;
        __bf16 buf[32];
#pragma unroll
        for (int c = 0; c < 32; ++c) buf[c] = (__bf16)src[c * PLANE];
        b16x8* dst = (b16x8*)(xT + (size_t)p * 64 + half * 32);
#pragma unroll
        for (int j = 0; j < 4; ++j) dst[j] = ((const b16x8*)buf)[j];
    } else {
        int i = (bid - 576) * 256 + threadIdx.x;
        if (i < 36864) {
            int e = i & 7, lane = (i >> 3) & 63, mt = (i >> 9) & 3, ks = (i >> 11) & 1, k = i >> 12;
            int o = mt * 16 + (lane & 15);
            int c = ks * 32 + ((lane >> 4) << 3) + e;
            wAB[i] = (__bf16)weight[o * 576 + c * 9 + k];
        }
        if (i < 18432) {
            int e = i & 7, lane = (i >> 3) & 63, mt = (i >> 9) & 1, ks = (i >> 10) & 1, t = i >> 11;
            int ch = mt * 16 + (lane & 15);
            int c  = ks * 32 + ((lane >> 4) << 3) + e;
            wAO[i] = (ch < 27) ? (__bf16)w_off[ch * 576 + c * 9 + t] : (__bf16)(0.f);
        }
    }
}

// R11 deform = R10 + zero-VGPR-cost pipeline deepening. R10 post-mortem:
// ks1 octets (o00-o11) were loaded at the TOP of the iteration consuming
// them: ~120 cyc cover vs ~120 cyc LDS latency -> marginal. R9's fix (second
// register set) spilled. THIS fix: load o(k+1) into the SAME o00-o11 regs
// right AFTER the fo(k) combine consumes them (WAR dep keeps order; sl/inw
// for k+1 already computed by CALC(k+1) mid-iteration). Cover becomes
// MFMA-fo + next iter's a-loads + om reads + fe combine + MFMA-fe ~ 250+
// cyc -- symmetric with the e-octets, no extra live registers. Compiler
// can't do this itself across the unroll-1 back-edge.
__global__ __launch_bounds__(256, 5)
void deform_mfma(const __bf16* __restrict__ xT,
                 const __bf16* __restrict__ wAO,
                 const float* __restrict__ b_off,
                 const __bf16* __restrict__ wAB,
                 const float* __restrict__ bias,
                 float* __restrict__ out) {
    __shared__ __align__(16) unsigned char smemWin[WBYTES];   // 24576 B
    __shared__ float omL[4][27 * 16];                          // 6912 B, wave-private

    int tid  = threadIdx.x;
    int lane = tid & 63;
    int s    = __builtin_amdgcn_readfirstlane(tid >> 6);   // strip = row in tile
    int n    = lane & 15;    // pixel col within strip / MFMA col
    int q    = lane >> 4;    // octet: channels q*8..q*8+7 (ks0) / +32 (ks1)

    int t    = swz(blockIdx.x);
    int b    = t / 144;            // 144 tiles per image (24 row-quads x 6 col-tiles)
    int rem  = t - b * 144;
    int rq   = rem / 6;
    int ct   = rem - rq * 6;
    int h0   = rq * 4;             // tile top row
    int c0   = ct * 16;            // tile left col
    int hrow = h0 + s;             // this strip's row
    int w    = c0 + n;             // this lane's col

    const __bf16* xTimg = xT + (size_t)b * PLANE * 64;
    const __bf16* xTb   = xTimg + q * 8;   // fallback gather base (ks0 octet)

    const b16x8* wAOv = (const b16x8*)wAO;
    const b16x8* wABv = (const b16x8*)wAB;
    int boff = q * 16;   // ks0 byte offset within a pixel line; ks1 at boff+64

#define LDSRD(sl_, off_) (*(const b16x8*)(smemWin + (sl_) * 128 + ((off_) ^ (((sl_) & 7) << 4))))

    // ---------------- Stage window: 189 px (pad 192) * 128 B, coalesced -----
    // 1536 chunks = exactly 6 per thread. Swizzled write: byte chunk
    // j*16 ^ (pix&7)<<4 spreads phase reads across 8 bank groups.
#pragma unroll
    for (int r2 = 0; r2 < 6; ++r2) {
        int idx = tid + r2 * 256;
        int pix = idx >> 3, j = idx & 7;
        int yw = pix / WC, xw = pix - yw * WC;          // pad rows clamp below
        int ys = min(max(h0 - 2 + yw, 0), Hs - 1);
        int xs = min(max(c0 - 2 + xw, 0), Ws - 1);
        b16x8 v = *(const b16x8*)(xTimg + ((ys * Ws + xs) * 64) + j * 8);
        *(b16x8*)(smemWin + pix * 128 + ((j * 16) ^ ((pix & 7) << 4))) = v;
    }
    __syncthreads();

    // ---------------- Phase A: offset conv via MFMA (full K) ----------------
    // Taps sample (hrow-1+ky, w-1+kx): window rows 1..6, cols 1..18.
    f32x4 accA0 = {0.f, 0.f, 0.f, 0.f};
    f32x4 accA1 = {0.f, 0.f, 0.f, 0.f};
    const b16x8 ZER = {};

#pragma unroll 3
    for (int tt = 0; tt < 9; ++tt) {
        int ky = tt / 3, kx = tt - ky * 3;
        int yy = hrow - 1 + ky, xx = w - 1 + kx;
        bool mk = (yy >= 0 && yy < Hs && xx >= 0 && xx < Ws);   // zero-pad conv
        int slA = (s + 1 + ky) * WC + (n + 1 + kx);
        b16x8 bf0 = LDSRD(slA, boff);
        b16x8 bf1 = LDSRD(slA, boff + 64);
        bf0 = mk ? bf0 : ZER;
        bf1 = mk ? bf1 : ZER;
        b16x8 af0 = wAOv[((tt * 2 + 0) * 2 + 0) * 64 + lane];
        b16x8 af1 = wAOv[((tt * 2 + 0) * 2 + 1) * 64 + lane];
        b16x8 af2 = wAOv[((tt * 2 + 1) * 2 + 0) * 64 + lane];
        b16x8 af3 = wAOv[((tt * 2 + 1) * 2 + 1) * 64 + lane];
        accA0 = __builtin_amdgcn_mfma_f32_16x16x32_bf16(af0, bf0, accA0, 0, 0, 0);
        accA1 = __builtin_amdgcn_mfma_f32_16x16x32_bf16(af1, bf0, accA1, 0, 0, 0);
        accA0 = __builtin_amdgcn_mfma_f32_16x16x32_bf16(af2, bf1, accA0, 0, 0, 0);
        accA1 = __builtin_amdgcn_mfma_f32_16x16x32_bf16(af3, bf1, accA1, 0, 0, 0);
    }
    // om is wave-private: no barrier needed (same wave writes then reads).
    float* omW = &omL[s][0];
#pragma unroll
    for (int rg = 0; rg < 4; ++rg) { int ch = q * 4 + rg;      omW[ch * 16 + n] = accA0[rg] + b_off[ch]; }
#pragma unroll
    for (int rg = 0; rg < 4; ++rg) { int ch = 16 + q * 4 + rg; if (ch < 27) omW[ch * 16 + n] = accA1[rg] + b_off[ch]; }

    // ---------------- Phase B: pipelined sampling + main conv ---------------
    f32x4 acc0 = {0.f, 0.f, 0.f, 0.f};
    f32x4 acc1 = {0.f, 0.f, 0.f, 0.f};
    f32x4 acc2 = {0.f, 0.f, 0.f, 0.f};
    f32x4 acc3 = {0.f, 0.f, 0.f, 0.f};

    float W00, W01, W10, W11;   // NEXT tap bilinear weights (after CALC)
    int   sl, y0r, x0r;         // next tap window slot / raw corner coords
    bool  inw;                  // next tap fully-in-window predicate
    b16x8 e00, e01, e10, e11;   // tap k ks0 octets (loaded one tap ahead)
    b16x8 o00, o01, o10, o11;   // tap k ks1 octets (loaded one tap ahead)

#define CALC_FROM(dy, dx, mo, kk) do {                                            \
        float m  = 1.f / (1.f + __expf(-(mo)));                                   \
        int ky = (kk) / 3, kx = (kk) - ky * 3;                                    \
        float ysf = (float)(hrow - 1 + ky) + (dy);                                \
        float xsf = (float)(w    - 1 + kx) + (dx);                                \
        float y0f = floorf(ysf), x0f = floorf(xsf);                               \
        float ly = ysf - y0f, lx = xsf - x0f;                                     \
        float hy = 1.f - ly, hx = 1.f - lx;                                       \
        y0r = (int)y0f; x0r = (int)x0f;                                           \
        int y1 = y0r + 1, x1 = x0r + 1;                                           \
        bool vy0 = (y0r >= 0) && (y0r < Hs), vy1 = (y1 >= 0) && (y1 < Hs);        \
        bool vx0 = (x0r >= 0) && (x0r < Ws), vx1 = (x1 >= 0) && (x1 < Ws);        \
        W00 = (vy0 && vx0) ? m * hy * hx : 0.f;                                   \
        W01 = (vy0 && vx1) ? m * hy * lx : 0.f;                                   \
        W10 = (vy1 && vx0) ? m * ly * hx : 0.f;                                   \
        W11 = (vy1 && vx1) ? m * ly * lx : 0.f;                                   \
        inw = (y0r >= h0 - 2) && (y1 <= h0 + 6) && (x0r >= c0 - 2) && (x1 <= c0 + 18); \
        sl  = (y0r - (h0 - 2)) * WC + (x0r - (c0 - 2));                           \
    } while (0)

    // Load 4 corner octets at element-offset ELO (0=ks0, 32=ks1) for the tap
    // described by sl/inw: LDS fast path, exact clamped-global fallback.
#define LOAD4(d0, d1, d2, d3, OFF, ELO) do {                                      \
        if (inw) {                                                                \
            d0 = LDSRD(sl, OFF);          d1 = LDSRD(sl + 1, OFF);                \
            d2 = LDSRD(sl + WC, OFF);     d3 = LDSRD(sl + WC + 1, OFF);           \
        } else {                                                                  \
            int y0c = min(max(y0r, 0), Hs - 1), y1c = min(max(y0r + 1, 0), Hs - 1); \
            int x0c = min(max(x0r, 0), Ws - 1), x1c = min(max(x0r + 1, 0), Ws - 1); \
            d0 = *(const b16x8*)(xTb + (y0c * Ws + x0c) * 64 + (ELO));            \
            d1 = *(const b16x8*)(xTb + (y0c * Ws + x1c) * 64 + (ELO));            \
            d2 = *(const b16x8*)(xTb + (y1c * Ws + x0c) * 64 + (ELO));            \
            d3 = *(const b16x8*)(xTb + (y1c * Ws + x1c) * 64 + (ELO));            \
        }                                                                         \
    } while (0)

    {   // prologue: tap 0 addresses + BOTH octet sets
        float dy0 = omW[0 * 16 + n], dx0 = omW[1 * 16 + n], mo0 = omW[18 * 16 + n];
        CALC_FROM(dy0, dx0, mo0, 0);
        LOAD4(e00, e01, e10, e11, boff, 0);
        LOAD4(o00, o01, o10, o11, boff + 64, 32);
    }

#pragma unroll 1
    for (int k = 0; k < 9; ++k) {
        b16x8 a0 = wABv[(k * 8 + 0) * 64 + lane];
        b16x8 a1 = wABv[(k * 8 + 1) * 64 + lane];
        b16x8 a2 = wABv[(k * 8 + 2) * 64 + lane];
        b16x8 a3 = wABv[(k * 8 + 3) * 64 + lane];

        // prefetch tap k+1's om triple (latency hidden behind combine+MFMA)
        int kn = (k < 8) ? (k + 1) : 8;
        float dyN = omW[(2 * kn) * 16 + n];
        float dxN = omW[(2 * kn + 1) * 16 + n];
        float moN = omW[(18 + kn) * 16 + n];

        float V00 = W00, V01 = W01, V10 = W10, V11 = W11;   // tap k weights

        b16x8 fe;
#pragma unroll
        for (int j = 0; j < 8; ++j)
            fe[j] = (__bf16)((float)e00[j] * V00 + (float)e01[j] * V01 +
                             (float)e10[j] * V10 + (float)e11[j] * V11);
        acc0 = __builtin_amdgcn_mfma_f32_16x16x32_bf16(a0, fe, acc0, 0, 0, 0);
        acc1 = __builtin_amdgcn_mfma_f32_16x16x32_bf16(a1, fe, acc1, 0, 0, 0);
        acc2 = __builtin_amdgcn_mfma_f32_16x16x32_bf16(a2, fe, acc2, 0, 0, 0);
        acc3 = __builtin_amdgcn_mfma_f32_16x16x32_bf16(a3, fe, acc3, 0, 0, 0);

        if (k < 8) {   // CALC(k+1) + its ks0 octets (e-regs free: fe consumed them)
            CALC_FROM(dyN, dxN, moN, k + 1);
            LOAD4(e00, e01, e10, e11, boff, 0);
        }

        // a4-a7 loaded late (short live range -> lower peak VGPR pressure)
        b16x8 a4 = wABv[(k * 8 + 4) * 64 + lane];
        b16x8 a5 = wABv[(k * 8 + 5) * 64 + lane];
        b16x8 a6 = wABv[(k * 8 + 6) * 64 + lane];
        b16x8 a7 = wABv[(k * 8 + 7) * 64 + lane];

        b16x8 fo;
#pragma unroll
        for (int j = 0; j < 8; ++j)
            fo[j] = (__bf16)((float)o00[j] * V00 + (float)o01[j] * V01 +
                             (float)o10[j] * V10 + (float)o11[j] * V11);

        if (k < 8) {   // ks1 octets for tap k+1 into the SAME o-regs (WAR on
                       // the fo combine above keeps order; ~250 cyc of cover
                       // before next iteration's fo combine reads them)
            LOAD4(o00, o01, o10, o11, boff + 64, 32);
        }

        acc0 = __builtin_amdgcn_mfma_f32_16x16x32_bf16(a4, fo, acc0, 0, 0, 0);
        acc1 = __builtin_amdgcn_mfma_f32_16x16x32_bf16(a5, fo, acc1, 0, 0, 0);
        acc2 = __builtin_amdgcn_mfma_f32_16x16x32_bf16(a6, fo, acc2, 0, 0, 0);
        acc3 = __builtin_amdgcn_mfma_f32_16x16x32_bf16(a7, fo, acc3, 0, 0, 0);
    }
#undef LOAD4
#undef CALC_FROM
#undef LDSRD

    // ---------------- Epilogue: direct store (no exchange) ------------------
    int ob = b * (COUT_ * PLANE) + hrow * Ws + w;
    f32x4 bs0 = *(const f32x4*)&bias[q * 4];
    f32x4 bs1 = *(const f32x4*)&bias[16 + q * 4];
    f32x4 bs2 = *(const f32x4*)&bias[32 + q * 4];
    f32x4 bs3 = *(const f32x4*)&bias[48 + q * 4];
#pragma unroll
    for (int rg = 0; rg < 4; ++rg) { int o =      q * 4 + rg; out[ob + o * PLANE] = acc0[rg] + bs0[rg]; }
#pragma unroll
    for (int rg = 0; rg < 4; ++rg) { int o = 16 + q * 4 + rg; out[ob + o * PLANE] = acc1[rg] + bs1[rg]; }
#pragma unroll
    for (int rg = 0; rg < 4; ++rg) { int o = 32 + q * 4 + rg; out[ob + o * PLANE] = acc2[rg] + bs2[rg]; }
#pragma unroll
    for (int rg = 0; rg < 4; ++rg) { int o = 48 + q * 4 + rg; out[ob + o * PLANE] = acc3[rg] + bs3[rg]; }
}

extern "C" void kernel_launch(void* const* d_in, const int* in_sizes, int n_in,
                              void* d_out, int out_size, void* d_ws, size_t ws_size,
                              hipStream_t stream) {
    const float* x      = (const float*)d_in[0];
    const float* w_off  = (const float*)d_in[1];
    const float* b_off  = (const float*)d_in[2];
    const float* weight = (const float*)d_in[3];
    const float* bias   = (const float*)d_in[4];
    float* out = (float*)d_out;

    char* ws = (char*)d_ws;
    __bf16* wAB = (__bf16*)ws;               //  73728 B
    __bf16* wAO = (__bf16*)(ws + 73728);     //  36864 B
    __bf16* xT  = (__bf16*)(ws + 131072);    // 9437184 B (bf16 channel-last)

    prep_xpose<<<720, 256, 0, stream>>>(x, weight, w_off, xT, wAB, wAO);
    deform_mfma<<<NBLK, 256, 0, stream>>>(xT, wAO, b_off, wAB, bias, out);
}

// Round 12
// 107.971 us; speedup vs baseline: 1.0793x; 1.0793x over previous
//
#include <hip/hip_runtime.h>
#include <math.h>

typedef __bf16 b16x8 __attribute__((ext_vector_type(8)));
typedef float  f32x4 __attribute__((ext_vector_type(4)));
typedef float  f32x2 __attribute__((ext_vector_type(2)));

#define B_    8
#define CIN_  64
#define COUT_ 64
#define Hs    96
#define Ws    96
#define PLANE (Hs*Ws)        // 9216
#define IMG   (CIN_*PLANE)   // 589824
#define NP    (B_*PLANE)     // 73728
#define NBLK  (NP/64)        // 1152 blocks, 64 px each as a 4-row x 16-col tile

// LDS window for a 4x16 tile with +/-1 offset margin:
// rows h0-2..h0+6 (9), cols c0-2..c0+18 (21). Offsets are ~N(0,0.24) so
// |d|>1 is ~3e-5; the exact global fallback handles those lanes.
#define WR 9
#define WC 21
#define WPIX (WR*WC)         // 189
#define WSTG 192             // padded to 6 full 256-thread stage rounds
#define WBYTES (WSTG*128)    // 24576 B

__device__ __forceinline__ int swz(int bid) { return (bid & 7) * (NBLK / 8) + (bid >> 3); }

// prep (R9/R10): xpose at HALF a pixel (32 channels) per thread, blocks
// [0,576) -> 2.8 blocks/CU. Reads: even/odd lanes split channel halves,
// 2x128-B segments per instr. Writes: 64 B/lane, consecutive lanes
// contiguous (4 KB per wave-instr). [576,720) = weight repack.
__global__ void prep_xpose(const float* __restrict__ x,
                           const float* __restrict__ weight, const float* __restrict__ w_off,
                           __bf16* __restrict__ xT,
                           __bf16* __restrict__ wAB, __bf16* __restrict__ wAO) {
    int bid = blockIdx.x;
    if (bid < 576) {
        int idx  = bid * 256 + threadIdx.x;   // 147456 = 2*NP half-pixel jobs
        int p    = idx >> 1;                  // pixel
        int half = idx & 1;                   // channel half: half*32..+31
        int b = p / PLANE, r = p - b * PLANE;
        const float* src = x + b * IMG + (size_t)half * 32 * PLANE + r;
        __bf16 buf[32];
#pragma unroll
        for (int c = 0; c < 32; ++c) buf[c] = (__bf16)src[c * PLANE];
        b16x8* dst = (b16x8*)(xT + (size_t)p * 64 + half * 32);
#pragma unroll
        for (int j = 0; j < 4; ++j) dst[j] = ((const b16x8*)buf)[j];
    } else {
        int i = (bid - 576) * 256 + threadIdx.x;
        if (i < 36864) {
            int e = i & 7, lane = (i >> 3) & 63, mt = (i >> 9) & 3, ks = (i >> 11) & 1, k = i >> 12;
            int o = mt * 16 + (lane & 15);
            int c = ks * 32 + ((lane >> 4) << 3) + e;
            wAB[i] = (__bf16)weight[o * 576 + c * 9 + k];
        }
        if (i < 18432) {
            int e = i & 7, lane = (i >> 3) & 63, mt = (i >> 9) & 1, ks = (i >> 10) & 1, t = i >> 11;
            int ch = mt * 16 + (lane & 15);
            int c  = ks * 32 + ((lane >> 4) << 3) + e;
            wAO[i] = (ch < 27) ? (__bf16)w_off[ch * 576 + c * 9 + t] : (__bf16)(0.f);
        }
    }
}

// R12 deform = R10/R8 deform VERBATIM -- the measured optimum (108.98 us).
// Pipeline-depth boundary is now triple-confirmed:
//   R9  (2nd reg set for o-octets)          -> spill, 48 VGPR, 238 MB scratch
//   R11 (same-reg reload after fo combine)  -> live-range across back-edge,
//                                              fo->MFMA serialization, -7.5us
// At 5 blocks/CU (LDS floor 31.5 KB), R8's schedule -- e-octets one-tap-ahead,
// o-octets same-iteration-top -- is the register-feasible optimum. Occupancy
// cap: 6 blocks/CU needs <=27.3 KB LDS (only reachable by bf16-izing om;
// absmax risk). Remaining budget: fill ~44 (harness) + overhead ~24 +
// deform ~34 (latency plateau, bounded) + prep ~7 (near BW floor).
__global__ __launch_bounds__(256, 5)
void deform_mfma(const __bf16* __restrict__ xT,
                 const __bf16* __restrict__ wAO,
                 const float* __restrict__ b_off,
                 const __bf16* __restrict__ wAB,
                 const float* __restrict__ bias,
                 float* __restrict__ out) {
    __shared__ __align__(16) unsigned char smemWin[WBYTES];   // 24576 B
    __shared__ float omL[4][27 * 16];                          // 6912 B, wave-private

    int tid  = threadIdx.x;
    int lane = tid & 63;
    int s    = __builtin_amdgcn_readfirstlane(tid >> 6);   // strip = row in tile
    int n    = lane & 15;    // pixel col within strip / MFMA col
    int q    = lane >> 4;    // octet: channels q*8..q*8+7 (ks0) / +32 (ks1)

    int t    = swz(blockIdx.x);
    int b    = t / 144;            // 144 tiles per image (24 row-quads x 6 col-tiles)
    int rem  = t - b * 144;
    int rq   = rem / 6;
    int ct   = rem - rq * 6;
    int h0   = rq * 4;             // tile top row
    int c0   = ct * 16;            // tile left col
    int hrow = h0 + s;             // this strip's row
    int w    = c0 + n;             // this lane's col

    const __bf16* xTimg = xT + (size_t)b * PLANE * 64;
    const __bf16* xTb   = xTimg + q * 8;   // fallback gather base (ks0 octet)

    const b16x8* wAOv = (const b16x8*)wAO;
    const b16x8* wABv = (const b16x8*)wAB;
    int boff = q * 16;   // ks0 byte offset within a pixel line; ks1 at boff+64

#define LDSRD(sl_, off_) (*(const b16x8*)(smemWin + (sl_) * 128 + ((off_) ^ (((sl_) & 7) << 4))))

    // ---------------- Stage window: 189 px (pad 192) * 128 B, coalesced -----
    // 1536 chunks = exactly 6 per thread. Swizzled write: byte chunk
    // j*16 ^ (pix&7)<<4 spreads phase reads across 8 bank groups.
#pragma unroll
    for (int r2 = 0; r2 < 6; ++r2) {
        int idx = tid + r2 * 256;
        int pix = idx >> 3, j = idx & 7;
        int yw = pix / WC, xw = pix - yw * WC;          // pad rows clamp below
        int ys = min(max(h0 - 2 + yw, 0), Hs - 1);
        int xs = min(max(c0 - 2 + xw, 0), Ws - 1);
        b16x8 v = *(const b16x8*)(xTimg + ((ys * Ws + xs) * 64) + j * 8);
        *(b16x8*)(smemWin + pix * 128 + ((j * 16) ^ ((pix & 7) << 4))) = v;
    }
    __syncthreads();

    // ---------------- Phase A: offset conv via MFMA (full K) ----------------
    // Taps sample (hrow-1+ky, w-1+kx): window rows 1..6, cols 1..18.
    f32x4 accA0 = {0.f, 0.f, 0.f, 0.f};
    f32x4 accA1 = {0.f, 0.f, 0.f, 0.f};
    const b16x8 ZER = {};

#pragma unroll 3
    for (int tt = 0; tt < 9; ++tt) {
        int ky = tt / 3, kx = tt - ky * 3;
        int yy = hrow - 1 + ky, xx = w - 1 + kx;
        bool mk = (yy >= 0 && yy < Hs && xx >= 0 && xx < Ws);   // zero-pad conv
        int slA = (s + 1 + ky) * WC + (n + 1 + kx);
        b16x8 bf0 = LDSRD(slA, boff);
        b16x8 bf1 = LDSRD(slA, boff + 64);
        bf0 = mk ? bf0 : ZER;
        bf1 = mk ? bf1 : ZER;
        b16x8 af0 = wAOv[((tt * 2 + 0) * 2 + 0) * 64 + lane];
        b16x8 af1 = wAOv[((tt * 2 + 0) * 2 + 1) * 64 + lane];
        b16x8 af2 = wAOv[((tt * 2 + 1) * 2 + 0) * 64 + lane];
        b16x8 af3 = wAOv[((tt * 2 + 1) * 2 + 1) * 64 + lane];
        accA0 = __builtin_amdgcn_mfma_f32_16x16x32_bf16(af0, bf0, accA0, 0, 0, 0);
        accA1 = __builtin_amdgcn_mfma_f32_16x16x32_bf16(af1, bf0, accA1, 0, 0, 0);
        accA0 = __builtin_amdgcn_mfma_f32_16x16x32_bf16(af2, bf1, accA0, 0, 0, 0);
        accA1 = __builtin_amdgcn_mfma_f32_16x16x32_bf16(af3, bf1, accA1, 0, 0, 0);
    }
    // om is wave-private: no barrier needed (same wave writes then reads).
    float* omW = &omL[s][0];
#pragma unroll
    for (int rg = 0; rg < 4; ++rg) { int ch = q * 4 + rg;      omW[ch * 16 + n] = accA0[rg] + b_off[ch]; }
#pragma unroll
    for (int rg = 0; rg < 4; ++rg) { int ch = 16 + q * 4 + rg; if (ch < 27) omW[ch * 16 + n] = accA1[rg] + b_off[ch]; }

    // ---------------- Phase B: pipelined sampling + main conv ---------------
    f32x4 acc0 = {0.f, 0.f, 0.f, 0.f};
    f32x4 acc1 = {0.f, 0.f, 0.f, 0.f};
    f32x4 acc2 = {0.f, 0.f, 0.f, 0.f};
    f32x4 acc3 = {0.f, 0.f, 0.f, 0.f};

    float W00, W01, W10, W11;   // current tap bilinear weights (mask folded)
    int   sl, y0r, x0r;         // current tap window slot / raw corner coords
    bool  inw;                  // current tap fully-in-window predicate
    b16x8 e00, e01, e10, e11;   // current tap ks0 octets (prefetched)

#define CALC_FROM(dy, dx, mo, kk) do {                                            \
        float m  = 1.f / (1.f + __expf(-(mo)));                                   \
        int ky = (kk) / 3, kx = (kk) - ky * 3;                                    \
        float ysf = (float)(hrow - 1 + ky) + (dy);                                \
        float xsf = (float)(w    - 1 + kx) + (dx);                                \
        float y0f = floorf(ysf), x0f = floorf(xsf);                               \
        float ly = ysf - y0f, lx = xsf - x0f;                                     \
        float hy = 1.f - ly, hx = 1.f - lx;                                       \
        y0r = (int)y0f; x0r = (int)x0f;                                           \
        int y1 = y0r + 1, x1 = x0r + 1;                                           \
        bool vy0 = (y0r >= 0) && (y0r < Hs), vy1 = (y1 >= 0) && (y1 < Hs);        \
        bool vx0 = (x0r >= 0) && (x0r < Ws), vx1 = (x1 >= 0) && (x1 < Ws);        \
        W00 = (vy0 && vx0) ? m * hy * hx : 0.f;                                   \
        W01 = (vy0 && vx1) ? m * hy * lx : 0.f;                                   \
        W10 = (vy1 && vx0) ? m * ly * hx : 0.f;                                   \
        W11 = (vy1 && vx1) ? m * ly * lx : 0.f;                                   \
        inw = (y0r >= h0 - 2) && (y1 <= h0 + 6) && (x0r >= c0 - 2) && (x1 <= c0 + 18); \
        sl  = (y0r - (h0 - 2)) * WC + (x0r - (c0 - 2));                           \
    } while (0)

    // Load 4 corner octets at element-offset ELO (0=ks0, 32=ks1) for the
    // current tap: LDS fast path, exact clamped-global fallback (execz-skipped).
#define LOAD4(d0, d1, d2, d3, OFF, ELO) do {                                      \
        if (inw) {                                                                \
            d0 = LDSRD(sl, OFF);          d1 = LDSRD(sl + 1, OFF);                \
            d2 = LDSRD(sl + WC, OFF);     d3 = LDSRD(sl + WC + 1, OFF);           \
        } else {                                                                  \
            int y0c = min(max(y0r, 0), Hs - 1), y1c = min(max(y0r + 1, 0), Hs - 1); \
            int x0c = min(max(x0r, 0), Ws - 1), x1c = min(max(x0r + 1, 0), Ws - 1); \
            d0 = *(const b16x8*)(xTb + (y0c * Ws + x0c) * 64 + (ELO));            \
            d1 = *(const b16x8*)(xTb + (y0c * Ws + x1c) * 64 + (ELO));            \
            d2 = *(const b16x8*)(xTb + (y1c * Ws + x0c) * 64 + (ELO));            \
            d3 = *(const b16x8*)(xTb + (y1c * Ws + x1c) * 64 + (ELO));            \
        }                                                                         \
    } while (0)

    {   // prologue: tap 0 addresses + ks0 octets
        float dy0 = omW[0 * 16 + n], dx0 = omW[1 * 16 + n], mo0 = omW[18 * 16 + n];
        CALC_FROM(dy0, dx0, mo0, 0);
        LOAD4(e00, e01, e10, e11, boff, 0);
    }

#pragma unroll 1
    for (int k = 0; k < 9; ++k) {
        b16x8 a0 = wABv[(k * 8 + 0) * 64 + lane];
        b16x8 a1 = wABv[(k * 8 + 1) * 64 + lane];
        b16x8 a2 = wABv[(k * 8 + 2) * 64 + lane];
        b16x8 a3 = wABv[(k * 8 + 3) * 64 + lane];

        // tap k's ks1 octets (current sl/inw), issued before the combine
        b16x8 o00, o01, o10, o11;
        LOAD4(o00, o01, o10, o11, boff + 64, 32);

        // prefetch tap k+1's om triple (latency hidden behind combine+MFMA)
        int kn = (k < 8) ? (k + 1) : 8;
        float dyN = omW[(2 * kn) * 16 + n];
        float dxN = omW[(2 * kn + 1) * 16 + n];
        float moN = omW[(18 + kn) * 16 + n];

        float V00 = W00, V01 = W01, V10 = W10, V11 = W11;   // save for fo

        b16x8 fe;
#pragma unroll
        for (int j = 0; j < 8; ++j)
            fe[j] = (__bf16)((float)e00[j] * W00 + (float)e01[j] * W01 +
                             (float)e10[j] * W10 + (float)e11[j] * W11);
        acc0 = __builtin_amdgcn_mfma_f32_16x16x32_bf16(a0, fe, acc0, 0, 0, 0);
        acc1 = __builtin_amdgcn_mfma_f32_16x16x32_bf16(a1, fe, acc1, 0, 0, 0);
        acc2 = __builtin_amdgcn_mfma_f32_16x16x32_bf16(a2, fe, acc2, 0, 0, 0);
        acc3 = __builtin_amdgcn_mfma_f32_16x16x32_bf16(a3, fe, acc3, 0, 0, 0);

        if (k < 8) {   // CALC(k+1) + its ks0 octets; covered by fo combine+MFMAs
            CALC_FROM(dyN, dxN, moN, k + 1);
            LOAD4(e00, e01, e10, e11, boff, 0);
        }

        // a4-a7 loaded late (short live range -> lower peak VGPR pressure)
        b16x8 a4 = wABv[(k * 8 + 4) * 64 + lane];
        b16x8 a5 = wABv[(k * 8 + 5) * 64 + lane];
        b16x8 a6 = wABv[(k * 8 + 6) * 64 + lane];
        b16x8 a7 = wABv[(k * 8 + 7) * 64 + lane];

        b16x8 fo;
#pragma unroll
        for (int j = 0; j < 8; ++j)
            fo[j] = (__bf16)((float)o00[j] * V00 + (float)o01[j] * V01 +
                             (float)o10[j] * V10 + (float)o11[j] * V11);
        acc0 = __builtin_amdgcn_mfma_f32_16x16x32_bf16(a4, fo, acc0, 0, 0, 0);
        acc1 = __builtin_amdgcn_mfma_f32_16x16x32_bf16(a5, fo, acc1, 0, 0, 0);
        acc2 = __builtin_amdgcn_mfma_f32_16x16x32_bf16(a6, fo, acc2, 0, 0, 0);
        acc3 = __builtin_amdgcn_mfma_f32_16x16x32_bf16(a7, fo, acc3, 0, 0, 0);
    }
#undef LOAD4
#undef CALC_FROM
#undef LDSRD

    // ---------------- Epilogue: direct store (no exchange) ------------------
    int ob = b * (COUT_ * PLANE) + hrow * Ws + w;
    f32x4 bs0 = *(const f32x4*)&bias[q * 4];
    f32x4 bs1 = *(const f32x4*)&bias[16 + q * 4];
    f32x4 bs2 = *(const f32x4*)&bias[32 + q * 4];
    f32x4 bs3 = *(const f32x4*)&bias[48 + q * 4];
#pragma unroll
    for (int rg = 0; rg < 4; ++rg) { int o =      q * 4 + rg; out[ob + o * PLANE] = acc0[rg] + bs0[rg]; }
#pragma unroll
    for (int rg = 0; rg < 4; ++rg) { int o = 16 + q * 4 + rg; out[ob + o * PLANE] = acc1[rg] + bs1[rg]; }
#pragma unroll
    for (int rg = 0; rg < 4; ++rg) { int o = 32 + q * 4 + rg; out[ob + o * PLANE] = acc2[rg] + bs2[rg]; }
#pragma unroll
    for (int rg = 0; rg < 4; ++rg) { int o = 48 + q * 4 + rg; out[ob + o * PLANE] = acc3[rg] + bs3[rg]; }
}

extern "C" void kernel_launch(void* const* d_in, const int* in_sizes, int n_in,
                              void* d_out, int out_size, void* d_ws, size_t ws_size,
                              hipStream_t stream) {
    const float* x      = (const float*)d_in[0];
    const float* w_off  = (const float*)d_in[1];
    const float* b_off  = (const float*)d_in[2];
    const float* weight = (const float*)d_in[3];
    const float* bias   = (const float*)d_in[4];
    float* out = (float*)d_out;

    char* ws = (char*)d_ws;
    __bf16* wAB = (__bf16*)ws;               //  73728 B
    __bf16* wAO = (__bf16*)(ws + 73728);     //  36864 B
    __bf16* xT  = (__bf16*)(ws + 131072);    // 9437184 B (bf16 channel-last)

    prep_xpose<<<720, 256, 0, stream>>>(x, weight, w_off, xT, wAB, wAO);
    deform_mfma<<<NBLK, 256, 0, stream>>>(xT, wAO, b_off, wAB, bias, out);
}